// Round 4
// baseline (2516.598 us; speedup 1.0000x reference)
//
#include <hip/hip_runtime.h>
#include <math.h>

// Problem constants (from reference): N=100000, E=1600000, F_IN=8, H=128,
// L=4, E_FEAT=16, G=256, OUT=256. N/E derived from in_sizes at launch.
#define GG 256

__device__ __forceinline__ unsigned short f2bf(float x) {
  union { float f; unsigned u; } v; v.f = x;
  unsigned r = v.u + 0x7fff + ((v.u >> 16) & 1);   // round-to-nearest-even
  return (unsigned short)(r >> 16);
}

// ---------- h = x @ emb_W + emb_b  ([N,8]@[8,128]); also writes bf16 shadow ----------
__global__ __launch_bounds__(256) void k_emb(const float* __restrict__ x,
    const float* __restrict__ W, const float* __restrict__ b,
    float* __restrict__ h, unsigned short* __restrict__ hb, int N) {
  int idx = blockIdx.x * 256 + threadIdx.x;      // one float4 of output per thread
  if (idx >= N * 32) return;
  int n = idx >> 5, q = idx & 31;
  const float* xr = x + (size_t)n * 8;
  float xs[8];
#pragma unroll
  for (int k = 0; k < 8; ++k) xs[k] = xr[k];
  float4 acc = ((const float4*)b)[q];
#pragma unroll
  for (int k = 0; k < 8; ++k) {
    float4 w = ((const float4*)(W + (size_t)k * 128))[q];
    acc.x += xs[k] * w.x; acc.y += xs[k] * w.y;
    acc.z += xs[k] * w.z; acc.w += xs[k] * w.w;
  }
  ((float4*)h)[idx] = acc;
  ushort4 hv4 = make_ushort4(f2bf(acc.x), f2bf(acc.y), f2bf(acc.z), f2bf(acc.w));
  *(ushort4*)(hb + (size_t)idx * 4) = hv4;
}

// ---------- CSR build ----------
__global__ void k_hist(const int* __restrict__ dst, int* __restrict__ deg, int E) {
  int e = blockIdx.x * blockDim.x + threadIdx.x;
  if (e < E) atomicAdd(&deg[dst[e]], 1);
}

__global__ __launch_bounds__(256) void k_scan_reduce(const int* __restrict__ deg,
    int* __restrict__ bsum, int N) {
  __shared__ int sd[256];
  int i = blockIdx.x * 256 + threadIdx.x;
  sd[threadIdx.x] = (i < N) ? deg[i] : 0;
  __syncthreads();
  for (int s = 128; s > 0; s >>= 1) {
    if (threadIdx.x < s) sd[threadIdx.x] += sd[threadIdx.x + s];
    __syncthreads();
  }
  if (threadIdx.x == 0) bsum[blockIdx.x] = sd[0];
}

// single-block exclusive scan over nb (<=512) block sums
__global__ __launch_bounds__(512) void k_scan_mid(int* bsum, int nb) {
  __shared__ int sd[512];
  int t = threadIdx.x;
  int v = (t < nb) ? bsum[t] : 0;
  sd[t] = v; __syncthreads();
  for (int d = 1; d < 512; d <<= 1) {
    int xv = (t >= d) ? sd[t - d] : 0;
    __syncthreads();
    sd[t] += xv;
    __syncthreads();
  }
  if (t < nb) bsum[t] = sd[t] - v;   // exclusive
}

__global__ __launch_bounds__(256) void k_scan_final(const int* __restrict__ deg,
    const int* __restrict__ bsum, int* __restrict__ offs,
    int* __restrict__ cursor, int N) {
  __shared__ int sd[256];
  int t = threadIdx.x;
  int i = blockIdx.x * 256 + t;
  int v = (i < N) ? deg[i] : 0;
  sd[t] = v; __syncthreads();
  for (int d = 1; d < 256; d <<= 1) {           // Hillis-Steele inclusive scan
    int xv = (t >= d) ? sd[t - d] : 0;
    __syncthreads();
    sd[t] += xv;
    __syncthreads();
  }
  int off = bsum[blockIdx.x] + sd[t] - v;       // exclusive
  if (i < N) {
    offs[i] = off; cursor[i] = off;
    if (i == N - 1) offs[N] = off + v;
  }
}

__global__ void k_fill(const int* __restrict__ src, const int* __restrict__ dst,
    const float* __restrict__ attr, int* __restrict__ cursor,
    int* __restrict__ csrc, float* __restrict__ cattr, int E) {
  int e = blockIdx.x * blockDim.x + threadIdx.x;
  if (e >= E) return;
  int d = dst[e];
  int pos = atomicAdd(&cursor[d], 1);
  csrc[pos] = src[e];
  const float4* a = (const float4*)(attr + (size_t)e * 16);
  float4* o = (float4*)(cattr + (size_t)pos * 16);
  o[0] = a[0]; o[1] = a[1]; o[2] = a[2]; o[3] = a[3];
}

// ---------- graph boundaries (batch is sorted) ----------
__global__ void k_gstart(const int* __restrict__ batch, int* __restrict__ gstart,
                         int N, int Gn) {
  int i = blockIdx.x * blockDim.x + threadIdx.x;
  if (i >= N) return;
  int b = batch[i];
  if (i == 0) { for (int g = 0; g <= b; ++g) gstart[g] = 0; }
  else { int bp = batch[i - 1]; for (int g = bp + 1; g <= b; ++g) gstart[g] = i; }
  if (i == N - 1) { for (int g = b + 1; g <= Gn; ++g) gstart[g] = N; }
}

// ---------- fused edge embed + gather + relu + aggregate ----------
// hpa[n] = h[n] + sum_{j in CSR(n)} relu( attr[j]@edge_W + edge_b + h[src[j]] )
// 256-thread block = 2 nodes; per node, 2 waves, one column per thread
// (w[16] in 16 VGPRs -> high occupancy). bf16 gather: 1 dword per 2 lanes.
// Block 0 also zeroes the BN stats buffer (stream-ordered before k_gemm).
__global__ __launch_bounds__(256) void k_edge_agg(const float* __restrict__ h,
    const unsigned* __restrict__ hb32,       // bf16 shadow viewed as uint
    const float* __restrict__ cattr, const int* __restrict__ csrc,
    const int* __restrict__ offs, const float* __restrict__ eW,
    const float* __restrict__ eb, float* __restrict__ hpa,
    float* __restrict__ cstats, int N) {
  int t = threadIdx.x;
  if (blockIdx.x == 0) cstats[t] = 0.f;    // 256 floats: colsum|colsumsq
  int n = blockIdx.x * 2 + (t >> 7);
  if (n >= N) return;
  int c = t & 127;                          // column 0..127
  float w[16];
#pragma unroll
  for (int k = 0; k < 16; ++k) w[k] = eW[k * 128 + c];
  float bias = eb[c];
  int shr = (c & 1) * 16;
  const unsigned* hb_c = hb32 + (c >> 1);   // + s*64 per edge (row = 64 uints)
  int jb = offs[n], je = offs[n + 1];
  jb = __builtin_amdgcn_readfirstlane(jb);
  je = __builtin_amdgcn_readfirstlane(je);

#define EDGE(JJ, ACC)                                                       \
  {                                                                         \
    int s = csrc[(JJ)];                                                     \
    const float4* ap = (const float4*)(cattr + (size_t)(JJ) * 16);          \
    float4 a0 = ap[0], a1 = ap[1], a2 = ap[2], a3 = ap[3];                  \
    unsigned u = hb_c[(size_t)s * 64];                                      \
    float ev = bias;                                                        \
    ev += a0.x * w[0] + a0.y * w[1] + a0.z * w[2] + a0.w * w[3];            \
    ev += a1.x * w[4] + a1.y * w[5] + a1.z * w[6] + a1.w * w[7];            \
    ev += a2.x * w[8] + a2.y * w[9] + a2.z * w[10] + a2.w * w[11];          \
    ev += a3.x * w[12] + a3.y * w[13] + a3.z * w[14] + a3.w * w[15];        \
    union { unsigned uu; float ff; } cv;                                    \
    cv.uu = (u >> shr) << 16;                                               \
    ACC += fmaxf(ev + cv.ff, 0.f);                                          \
  }

  float acc0 = 0.f, acc1 = 0.f, acc2 = 0.f, acc3 = 0.f;
  int j = jb;
  for (; j + 4 <= je; j += 4) {
    EDGE(j, acc0)
    EDGE(j + 1, acc1)
    EDGE(j + 2, acc2)
    EDGE(j + 3, acc3)
  }
  for (; j < je; ++j) EDGE(j, acc0)
#undef EDGE
  size_t o = (size_t)n * 128 + c;
  hpa[o] = h[o] + ((acc0 + acc1) + (acc2 + acc3));
}

// ---------- in-place node GEMM: hpa <- hpa @ nn_W + nn_b, + BN stats ----------
// 8 rows per block; rows staged to LDS first so in-place write is safe.
// Epilogue: block-local column sum/sumsq -> atomicAdd into cstats.
__global__ __launch_bounds__(256) void k_gemm(float* __restrict__ hpa,
    const float* __restrict__ W, const float* __restrict__ b,
    float* __restrict__ cstats) {
  __shared__ float rows[8][128];
  __shared__ float wbuf[16][128];
  int t = threadIdx.x;
  size_t base = (size_t)blockIdx.x * (8 * 128);
  ((float4*)&rows[0][0])[t] = ((const float4*)(hpa + base))[t];
  int r = t >> 5;
  int cq = (t & 31) * 4;
  float4 acc = make_float4(0.f, 0.f, 0.f, 0.f);
  for (int kc = 0; kc < 8; ++kc) {
    __syncthreads();
    float4* wb4 = (float4*)&wbuf[0][0];
    const float4* gw = (const float4*)(W + (size_t)kc * 16 * 128);
    wb4[t] = gw[t];
    wb4[t + 256] = gw[t + 256];
    __syncthreads();
#pragma unroll
    for (int k = 0; k < 16; ++k) {
      float a = rows[r][kc * 16 + k];
      float4 wv = *(const float4*)&wbuf[k][cq];
      acc.x += a * wv.x; acc.y += a * wv.y;
      acc.z += a * wv.z; acc.w += a * wv.w;
    }
  }
  float4 bv = *(const float4*)(b + cq);
  acc.x += bv.x; acc.y += bv.y; acc.z += bv.z; acc.w += bv.w;
  ((float4*)(hpa + base))[r * 32 + (t & 31)] = acc;
  // BN stats epilogue: stage results back into rows[][] and column-reduce
  __syncthreads();
  *(float4*)&rows[r][cq] = acc;
  __syncthreads();
  if (t < 128) {
    float s = 0.f, s2 = 0.f;
#pragma unroll
    for (int rr = 0; rr < 8; ++rr) {
      float v = rows[rr][t];
      s += v; s2 += v * v;
    }
    atomicAdd(&cstats[t], s);
    atomicAdd(&cstats[128 + t], s2);
  }
}

// ---------- BN apply + exact GELU + residual: h += gelu(bn(hc)); bf16 shadow ----------
__global__ __launch_bounds__(256) void k_bn(const float* __restrict__ hc,
    const float* __restrict__ cstats,
    const float* __restrict__ g, const float* __restrict__ bb,
    float* __restrict__ h, unsigned short* __restrict__ hb, int N) {
  int idx = blockIdx.x * 256 + threadIdx.x;
  if (idx >= N * 32) return;
  int q = idx & 31;
  float invN = 1.f / (float)N;
  float4 cs = ((const float4*)cstats)[q];
  float4 cq = ((const float4*)cstats)[q + 32];
  float4 gv = ((const float4*)g)[q];
  float4 bv = ((const float4*)bb)[q];
  float4 v = ((const float4*)hc)[idx];
  float4 hv = ((const float4*)h)[idx];
#define BN1(X)                                                      \
  { float mu = cs.X * invN;                                         \
    float var = cq.X * invN - mu * mu;                              \
    float xn = (v.X - mu) * rsqrtf(var + 1e-5f) * gv.X + bv.X;      \
    hv.X += 0.5f * xn * (1.f + erff(xn * 0.70710678118654752f)); }
  BN1(x) BN1(y) BN1(z) BN1(w)
#undef BN1
  ((float4*)h)[idx] = hv;
  if (hb) {
    ushort4 hv4 = make_ushort4(f2bf(hv.x), f2bf(hv.y), f2bf(hv.z), f2bf(hv.w));
    *(ushort4*)(hb + (size_t)idx * 4) = hv4;
  }
}

// ---------- rep[g] = (sum over nodes of graph g of h[n]) @ lin_W + cnt*lin_b ----------
__global__ __launch_bounds__(256) void k_poolfinal(const float* __restrict__ h,
    const int* __restrict__ gstart, const float* __restrict__ W,
    const float* __restrict__ b, float* __restrict__ out) {
  int g = blockIdx.x;
  int t = threadIdx.x, c = t & 127, half = t >> 7;
  int n0 = gstart[g], n1 = gstart[g + 1];
  float s = 0.f;
  for (int n = n0 + half; n < n1; n += 2) s += h[(size_t)n * 128 + c];
  __shared__ float ls[256];
  __shared__ float pr[128];
  ls[t] = s; __syncthreads();
  if (t < 128) pr[t] = ls[t] + ls[t + 128];
  __syncthreads();
  float cnt = (float)(n1 - n0);
  float acc = cnt * b[t];
#pragma unroll 8
  for (int k = 0; k < 128; ++k) acc += pr[k] * W[(size_t)k * 256 + t];
  out[(size_t)g * 256 + t] = acc;
}

extern "C" void kernel_launch(void* const* d_in, const int* in_sizes, int n_in,
                              void* d_out, int out_size, void* d_ws, size_t ws_size,
                              hipStream_t stream) {
  const float* x     = (const float*)d_in[0];
  const int*   eidx  = (const int*)d_in[1];
  const float* eattr = (const float*)d_in[2];
  const int*   batch = (const int*)d_in[3];
  const float* embW  = (const float*)d_in[4];
  const float* embB  = (const float*)d_in[5];
  const float* edgeW = (const float*)d_in[6];
  const float* edgeB = (const float*)d_in[7];
  const float* nnW   = (const float*)d_in[8];
  const float* nnB   = (const float*)d_in[9];
  const float* bnG   = (const float*)d_in[10];
  const float* bnB   = (const float*)d_in[11];
  const float* linW  = (const float*)d_in[12];
  const float* linB  = (const float*)d_in[13];
  float* out = (float*)d_out;

  int N = in_sizes[0] / 8;
  int E = in_sizes[1] / 2;
  const int* src = eidx;
  const int* dst = eidx + E;

  // workspace carve-up (~240 MB)
  char* wptr = (char*)d_ws;
  auto alloc = [&](size_t bytes) {
    char* p = wptr; wptr += (bytes + 255) & ~(size_t)255; return p;
  };
  float* h      = (float*)alloc((size_t)N * 128 * 4);
  float* hpa    = (float*)alloc((size_t)N * 128 * 4);   // also hc (in-place GEMM)
  unsigned short* hb = (unsigned short*)alloc((size_t)N * 128 * 2);  // bf16 shadow
  float* cattr  = (float*)alloc((size_t)E * 16 * 4);
  int*   csrc   = (int*)alloc((size_t)E * 4);
  int*   offs   = (int*)alloc((size_t)(N + 1) * 4);
  int*   cursor = (int*)alloc((size_t)N * 4);
  int*   deg    = (int*)alloc((size_t)N * 4);
  int nb = (N + 255) / 256;
  int*   bsum   = (int*)alloc((size_t)nb * 4);
  float* cstats = (float*)alloc(256 * 4);               // colsum | colsumsq
  int*   gstart = (int*)alloc((size_t)(GG + 1) * 4);

  int q32 = (N * 32 + 255) / 256;

  hipMemsetAsync(deg, 0, (size_t)N * 4, stream);
  k_emb<<<q32, 256, 0, stream>>>(x, embW, embB, h, hb, N);
  k_hist<<<(E + 255) / 256, 256, 0, stream>>>(dst, deg, E);
  k_scan_reduce<<<nb, 256, 0, stream>>>(deg, bsum, N);
  k_scan_mid<<<1, 512, 0, stream>>>(bsum, nb);
  k_scan_final<<<nb, 256, 0, stream>>>(deg, bsum, offs, cursor, N);
  k_fill<<<(E + 255) / 256, 256, 0, stream>>>(src, dst, eattr, cursor, csrc, cattr, E);
  k_gstart<<<(N + 255) / 256, 256, 0, stream>>>(batch, gstart, N, GG);

  for (int l = 0; l < 4; ++l) {
    k_edge_agg<<<(N + 1) / 2, 256, 0, stream>>>(h, (const unsigned*)hb, cattr, csrc,
        offs, edgeW + (size_t)l * 16 * 128, edgeB + (size_t)l * 128, hpa, cstats, N);
    k_gemm<<<(N + 7) / 8, 256, 0, stream>>>(hpa,
        nnW + (size_t)l * 128 * 128, nnB + (size_t)l * 128, cstats);
    k_bn<<<q32, 256, 0, stream>>>(hpa, cstats,
        bnG + (size_t)l * 128, bnB + (size_t)l * 128, h, (l == 3) ? nullptr : hb, N);
  }
  k_poolfinal<<<GG, 256, 0, stream>>>(h, gstart, linW, linB, out);
}

// Round 5
// 1545.986 us; speedup vs baseline: 1.6278x; 1.6278x over previous
//
#include <hip/hip_runtime.h>
#include <math.h>

// Problem constants (from reference): N=100000, E=1600000, F_IN=8, H=128,
// L=4, E_FEAT=16, G=256, OUT=256. N/E derived from in_sizes at launch.
#define GG 256

__device__ __forceinline__ unsigned short f2bf(float x) {
  union { float f; unsigned u; } v; v.f = x;
  unsigned r = v.u + 0x7fff + ((v.u >> 16) & 1);   // round-to-nearest-even
  return (unsigned short)(r >> 16);
}

// ---------- h = x @ emb_W + emb_b  ([N,8]@[8,128]); also writes bf16 shadow ----------
__global__ __launch_bounds__(256) void k_emb(const float* __restrict__ x,
    const float* __restrict__ W, const float* __restrict__ b,
    float* __restrict__ h, unsigned short* __restrict__ hb, int N) {
  int idx = blockIdx.x * 256 + threadIdx.x;      // one float4 of output per thread
  if (idx >= N * 32) return;
  int n = idx >> 5, q = idx & 31;
  const float* xr = x + (size_t)n * 8;
  float xs[8];
#pragma unroll
  for (int k = 0; k < 8; ++k) xs[k] = xr[k];
  float4 acc = ((const float4*)b)[q];
#pragma unroll
  for (int k = 0; k < 8; ++k) {
    float4 w = ((const float4*)(W + (size_t)k * 128))[q];
    acc.x += xs[k] * w.x; acc.y += xs[k] * w.y;
    acc.z += xs[k] * w.z; acc.w += xs[k] * w.w;
  }
  ((float4*)h)[idx] = acc;
  ushort4 hv4 = make_ushort4(f2bf(acc.x), f2bf(acc.y), f2bf(acc.z), f2bf(acc.w));
  *(ushort4*)(hb + (size_t)idx * 4) = hv4;
}

// ---------- CSR build ----------
__global__ void k_hist(const int* __restrict__ dst, int* __restrict__ deg, int E) {
  int e = blockIdx.x * blockDim.x + threadIdx.x;
  if (e < E) atomicAdd(&deg[dst[e]], 1);
}

__global__ __launch_bounds__(256) void k_scan_reduce(const int* __restrict__ deg,
    int* __restrict__ bsum, int N) {
  __shared__ int sd[256];
  int i = blockIdx.x * 256 + threadIdx.x;
  sd[threadIdx.x] = (i < N) ? deg[i] : 0;
  __syncthreads();
  for (int s = 128; s > 0; s >>= 1) {
    if (threadIdx.x < s) sd[threadIdx.x] += sd[threadIdx.x + s];
    __syncthreads();
  }
  if (threadIdx.x == 0) bsum[blockIdx.x] = sd[0];
}

// single-block exclusive scan over nb (<=512) block sums
__global__ __launch_bounds__(512) void k_scan_mid(int* bsum, int nb) {
  __shared__ int sd[512];
  int t = threadIdx.x;
  int v = (t < nb) ? bsum[t] : 0;
  sd[t] = v; __syncthreads();
  for (int d = 1; d < 512; d <<= 1) {
    int xv = (t >= d) ? sd[t - d] : 0;
    __syncthreads();
    sd[t] += xv;
    __syncthreads();
  }
  if (t < nb) bsum[t] = sd[t] - v;   // exclusive
}

__global__ __launch_bounds__(256) void k_scan_final(const int* __restrict__ deg,
    const int* __restrict__ bsum, int* __restrict__ offs,
    int* __restrict__ cursor, int N) {
  __shared__ int sd[256];
  int t = threadIdx.x;
  int i = blockIdx.x * 256 + t;
  int v = (i < N) ? deg[i] : 0;
  sd[t] = v; __syncthreads();
  for (int d = 1; d < 256; d <<= 1) {           // Hillis-Steele inclusive scan
    int xv = (t >= d) ? sd[t - d] : 0;
    __syncthreads();
    sd[t] += xv;
    __syncthreads();
  }
  int off = bsum[blockIdx.x] + sd[t] - v;       // exclusive
  if (i < N) {
    offs[i] = off; cursor[i] = off;
    if (i == N - 1) offs[N] = off + v;
  }
}

__global__ void k_fill(const int* __restrict__ src, const int* __restrict__ dst,
    const float* __restrict__ attr, int* __restrict__ cursor,
    int* __restrict__ csrc, float* __restrict__ cattr, int E) {
  int e = blockIdx.x * blockDim.x + threadIdx.x;
  if (e >= E) return;
  int d = dst[e];
  int pos = atomicAdd(&cursor[d], 1);
  csrc[pos] = src[e];
  const float4* a = (const float4*)(attr + (size_t)e * 16);
  float4* o = (float4*)(cattr + (size_t)pos * 16);
  o[0] = a[0]; o[1] = a[1]; o[2] = a[2]; o[3] = a[3];
}

// ---------- graph boundaries (batch is sorted) ----------
__global__ void k_gstart(const int* __restrict__ batch, int* __restrict__ gstart,
                         int N, int Gn) {
  int i = blockIdx.x * blockDim.x + threadIdx.x;
  if (i >= N) return;
  int b = batch[i];
  if (i == 0) { for (int g = 0; g <= b; ++g) gstart[g] = 0; }
  else { int bp = batch[i - 1]; for (int g = bp + 1; g <= b; ++g) gstart[g] = i; }
  if (i == N - 1) { for (int g = b + 1; g <= Gn; ++g) gstart[g] = N; }
}

// ---------- fused edge embed + gather + relu + aggregate ----------
// hpa[n] = h[n] + sum_{j in CSR(n)} relu( attr[j]@edge_W + edge_b + h[src[j]] )
// 256-thread block = 2 nodes; per node, 2 waves, one column per thread
// (w[16] in 16 VGPRs -> high occupancy). bf16 gather: 1 dword per 2 lanes.
// Block 0 also zeroes the BN stats buffer (stream-ordered before k_gemm).
__global__ __launch_bounds__(256) void k_edge_agg(const float* __restrict__ h,
    const unsigned* __restrict__ hb32,       // bf16 shadow viewed as uint
    const float* __restrict__ cattr, const int* __restrict__ csrc,
    const int* __restrict__ offs, const float* __restrict__ eW,
    const float* __restrict__ eb, float* __restrict__ hpa,
    float* __restrict__ cstats, int N) {
  int t = threadIdx.x;
  if (blockIdx.x == 0) cstats[t] = 0.f;    // 256 floats: colsum|colsumsq
  int n = blockIdx.x * 2 + (t >> 7);
  if (n >= N) return;
  int c = t & 127;                          // column 0..127
  float w[16];
#pragma unroll
  for (int k = 0; k < 16; ++k) w[k] = eW[k * 128 + c];
  float bias = eb[c];
  int shr = (c & 1) * 16;
  const unsigned* hb_c = hb32 + (c >> 1);   // + s*64 per edge (row = 64 uints)
  int jb = offs[n], je = offs[n + 1];
  jb = __builtin_amdgcn_readfirstlane(jb);
  je = __builtin_amdgcn_readfirstlane(je);

#define EDGE(JJ, ACC)                                                       \
  {                                                                         \
    int s = csrc[(JJ)];                                                     \
    const float4* ap = (const float4*)(cattr + (size_t)(JJ) * 16);          \
    float4 a0 = ap[0], a1 = ap[1], a2 = ap[2], a3 = ap[3];                  \
    unsigned u = hb_c[(size_t)s * 64];                                      \
    float ev = bias;                                                        \
    ev += a0.x * w[0] + a0.y * w[1] + a0.z * w[2] + a0.w * w[3];            \
    ev += a1.x * w[4] + a1.y * w[5] + a1.z * w[6] + a1.w * w[7];            \
    ev += a2.x * w[8] + a2.y * w[9] + a2.z * w[10] + a2.w * w[11];          \
    ev += a3.x * w[12] + a3.y * w[13] + a3.z * w[14] + a3.w * w[15];        \
    union { unsigned uu; float ff; } cv;                                    \
    cv.uu = (u >> shr) << 16;                                               \
    ACC += fmaxf(ev + cv.ff, 0.f);                                          \
  }

  float acc0 = 0.f, acc1 = 0.f, acc2 = 0.f, acc3 = 0.f;
  int j = jb;
  for (; j + 4 <= je; j += 4) {
    EDGE(j, acc0)
    EDGE(j + 1, acc1)
    EDGE(j + 2, acc2)
    EDGE(j + 3, acc3)
  }
  for (; j < je; ++j) EDGE(j, acc0)
#undef EDGE
  size_t o = (size_t)n * 128 + c;
  hpa[o] = h[o] + ((acc0 + acc1) + (acc2 + acc3));
}

// ---------- in-place node GEMM: hpa <- hpa @ nn_W + nn_b, + fused BN stats ----------
// Grid-stride over 32-row chunks; 4 rows x 4 cols per thread; rows transposed
// in LDS so the k-step is 2 ds_read_b128 + 16 FMA. BN stats accumulate in
// registers across chunks; ONE block-level reduce + 256 atomics per block
// (625 blocks -> 160k atomics total; the 3.2M-atomic R4 design was the bug).
__global__ __launch_bounds__(256) void k_gemm(float* __restrict__ hpa,
    const float* __restrict__ W, const float* __restrict__ b,
    float* __restrict__ cstats, int N) {
  __shared__ float rowsT[128][36];   // [k][row], padded: stride 144B (16B-aligned)
  __shared__ float wbuf[16][128];
  int t = threadIdx.x;
  int rg = t >> 5;                   // row group 0..7 (4 rows each)
  int cq = (t & 31) * 4;             // column quad
  float4 bv = *(const float4*)(b + cq);
  float sA0 = 0.f, sA1 = 0.f, sA2 = 0.f, sA3 = 0.f;
  float sQ0 = 0.f, sQ1 = 0.f, sQ2 = 0.f, sQ3 = 0.f;
  int nchunks = (N + 31) / 32;
  int lr = t >> 3;                   // load row 0..31
  int lk = (t & 7) * 16;             // load k offset
  for (int chunk = blockIdx.x; chunk < nchunks; chunk += gridDim.x) {
    int row0 = chunk * 32;
    __syncthreads();                 // prev chunk's rowsT reads done
    {
      int row = row0 + lr;
      float4 v0, v1, v2, v3;
      if (row < N) {
        const float4* gp = (const float4*)(hpa + (size_t)row * 128 + lk);
        v0 = gp[0]; v1 = gp[1]; v2 = gp[2]; v3 = gp[3];
      } else {
        v0 = v1 = v2 = v3 = make_float4(0.f, 0.f, 0.f, 0.f);
      }
      rowsT[lk + 0][lr] = v0.x;  rowsT[lk + 1][lr] = v0.y;
      rowsT[lk + 2][lr] = v0.z;  rowsT[lk + 3][lr] = v0.w;
      rowsT[lk + 4][lr] = v1.x;  rowsT[lk + 5][lr] = v1.y;
      rowsT[lk + 6][lr] = v1.z;  rowsT[lk + 7][lr] = v1.w;
      rowsT[lk + 8][lr] = v2.x;  rowsT[lk + 9][lr] = v2.y;
      rowsT[lk + 10][lr] = v2.z; rowsT[lk + 11][lr] = v2.w;
      rowsT[lk + 12][lr] = v3.x; rowsT[lk + 13][lr] = v3.y;
      rowsT[lk + 14][lr] = v3.z; rowsT[lk + 15][lr] = v3.w;
    }
    float4 acc0 = make_float4(0.f, 0.f, 0.f, 0.f);
    float4 acc1 = acc0, acc2 = acc0, acc3 = acc0;
    for (int kc = 0; kc < 8; ++kc) {
      __syncthreads();
      float4* wb4 = (float4*)&wbuf[0][0];
      const float4* gw = (const float4*)(W + (size_t)kc * 16 * 128);
      wb4[t] = gw[t];
      wb4[t + 256] = gw[t + 256];
      __syncthreads();
#pragma unroll
      for (int k = 0; k < 16; ++k) {
        float4 rv = *(const float4*)&rowsT[kc * 16 + k][rg * 4];
        float4 wv = *(const float4*)&wbuf[k][cq];
        acc0.x += rv.x * wv.x; acc0.y += rv.x * wv.y;
        acc0.z += rv.x * wv.z; acc0.w += rv.x * wv.w;
        acc1.x += rv.y * wv.x; acc1.y += rv.y * wv.y;
        acc1.z += rv.y * wv.z; acc1.w += rv.y * wv.w;
        acc2.x += rv.z * wv.x; acc2.y += rv.z * wv.y;
        acc2.z += rv.z * wv.z; acc2.w += rv.z * wv.w;
        acc3.x += rv.w * wv.x; acc3.y += rv.w * wv.y;
        acc3.z += rv.w * wv.z; acc3.w += rv.w * wv.w;
      }
    }
    int rowb = row0 + rg * 4;
#define EMIT(ACC, I)                                                        \
    {                                                                       \
      ACC.x += bv.x; ACC.y += bv.y; ACC.z += bv.z; ACC.w += bv.w;           \
      if (rowb + (I) < N) {                                                 \
        *(float4*)(hpa + (size_t)(rowb + (I)) * 128 + cq) = ACC;            \
        sA0 += ACC.x; sA1 += ACC.y; sA2 += ACC.z; sA3 += ACC.w;             \
        sQ0 += ACC.x * ACC.x; sQ1 += ACC.y * ACC.y;                         \
        sQ2 += ACC.z * ACC.z; sQ3 += ACC.w * ACC.w;                         \
      }                                                                     \
    }
    EMIT(acc0, 0) EMIT(acc1, 1) EMIT(acc2, 2) EMIT(acc3, 3)
#undef EMIT
  }
  // block-level stats reduction (reuse rowsT as scratch: needs 2048 floats)
  __syncthreads();
  float* sd = &rowsT[0][0];
  *(float4*)&sd[rg * 128 + cq] = make_float4(sA0, sA1, sA2, sA3);
  *(float4*)&sd[1024 + rg * 128 + cq] = make_float4(sQ0, sQ1, sQ2, sQ3);
  __syncthreads();
  if (t < 128) {
    float s = 0.f, s2 = 0.f;
#pragma unroll
    for (int r = 0; r < 8; ++r) {
      s += sd[r * 128 + t];
      s2 += sd[1024 + r * 128 + t];
    }
    atomicAdd(&cstats[t], s);
    atomicAdd(&cstats[128 + t], s2);
  }
}

// ---------- BN apply + exact GELU + residual: h += gelu(bn(hc)); bf16 shadow ----------
__global__ __launch_bounds__(256) void k_bn(const float* __restrict__ hc,
    const float* __restrict__ cstats,
    const float* __restrict__ g, const float* __restrict__ bb,
    float* __restrict__ h, unsigned short* __restrict__ hb, int N) {
  int idx = blockIdx.x * 256 + threadIdx.x;
  if (idx >= N * 32) return;
  int q = idx & 31;
  float invN = 1.f / (float)N;
  float4 cs = ((const float4*)cstats)[q];
  float4 cq = ((const float4*)cstats)[q + 32];
  float4 gv = ((const float4*)g)[q];
  float4 bv = ((const float4*)bb)[q];
  float4 v = ((const float4*)hc)[idx];
  float4 hv = ((const float4*)h)[idx];
#define BN1(X)                                                      \
  { float mu = cs.X * invN;                                         \
    float var = cq.X * invN - mu * mu;                              \
    float xn = (v.X - mu) * rsqrtf(var + 1e-5f) * gv.X + bv.X;      \
    hv.X += 0.5f * xn * (1.f + erff(xn * 0.70710678118654752f)); }
  BN1(x) BN1(y) BN1(z) BN1(w)
#undef BN1
  ((float4*)h)[idx] = hv;
  if (hb) {
    ushort4 hv4 = make_ushort4(f2bf(hv.x), f2bf(hv.y), f2bf(hv.z), f2bf(hv.w));
    *(ushort4*)(hb + (size_t)idx * 4) = hv4;
  }
}

// ---------- rep[g] = (sum over nodes of graph g of h[n]) @ lin_W + cnt*lin_b ----------
__global__ __launch_bounds__(256) void k_poolfinal(const float* __restrict__ h,
    const int* __restrict__ gstart, const float* __restrict__ W,
    const float* __restrict__ b, float* __restrict__ out) {
  int g = blockIdx.x;
  int t = threadIdx.x, c = t & 127, half = t >> 7;
  int n0 = gstart[g], n1 = gstart[g + 1];
  float s = 0.f;
  for (int n = n0 + half; n < n1; n += 2) s += h[(size_t)n * 128 + c];
  __shared__ float ls[256];
  __shared__ float pr[128];
  ls[t] = s; __syncthreads();
  if (t < 128) pr[t] = ls[t] + ls[t + 128];
  __syncthreads();
  float cnt = (float)(n1 - n0);
  float acc = cnt * b[t];
#pragma unroll 8
  for (int k = 0; k < 128; ++k) acc += pr[k] * W[(size_t)k * 256 + t];
  out[(size_t)g * 256 + t] = acc;
}

extern "C" void kernel_launch(void* const* d_in, const int* in_sizes, int n_in,
                              void* d_out, int out_size, void* d_ws, size_t ws_size,
                              hipStream_t stream) {
  const float* x     = (const float*)d_in[0];
  const int*   eidx  = (const int*)d_in[1];
  const float* eattr = (const float*)d_in[2];
  const int*   batch = (const int*)d_in[3];
  const float* embW  = (const float*)d_in[4];
  const float* embB  = (const float*)d_in[5];
  const float* edgeW = (const float*)d_in[6];
  const float* edgeB = (const float*)d_in[7];
  const float* nnW   = (const float*)d_in[8];
  const float* nnB   = (const float*)d_in[9];
  const float* bnG   = (const float*)d_in[10];
  const float* bnB   = (const float*)d_in[11];
  const float* linW  = (const float*)d_in[12];
  const float* linB  = (const float*)d_in[13];
  float* out = (float*)d_out;

  int N = in_sizes[0] / 8;
  int E = in_sizes[1] / 2;
  const int* src = eidx;
  const int* dst = eidx + E;

  // workspace carve-up (~240 MB)
  char* wptr = (char*)d_ws;
  auto alloc = [&](size_t bytes) {
    char* p = wptr; wptr += (bytes + 255) & ~(size_t)255; return p;
  };
  float* h      = (float*)alloc((size_t)N * 128 * 4);
  float* hpa    = (float*)alloc((size_t)N * 128 * 4);   // also hc (in-place GEMM)
  unsigned short* hb = (unsigned short*)alloc((size_t)N * 128 * 2);  // bf16 shadow
  float* cattr  = (float*)alloc((size_t)E * 16 * 4);
  int*   csrc   = (int*)alloc((size_t)E * 4);
  int*   offs   = (int*)alloc((size_t)(N + 1) * 4);
  int*   cursor = (int*)alloc((size_t)N * 4);
  int*   deg    = (int*)alloc((size_t)N * 4);
  int nb = (N + 255) / 256;
  int*   bsum   = (int*)alloc((size_t)nb * 4);
  float* cstats = (float*)alloc(256 * 4);               // colsum | colsumsq
  int*   gstart = (int*)alloc((size_t)(GG + 1) * 4);

  int q32 = (N * 32 + 255) / 256;

  hipMemsetAsync(deg, 0, (size_t)N * 4, stream);
  k_emb<<<q32, 256, 0, stream>>>(x, embW, embB, h, hb, N);
  k_hist<<<(E + 255) / 256, 256, 0, stream>>>(dst, deg, E);
  k_scan_reduce<<<nb, 256, 0, stream>>>(deg, bsum, N);
  k_scan_mid<<<1, 512, 0, stream>>>(bsum, nb);
  k_scan_final<<<nb, 256, 0, stream>>>(deg, bsum, offs, cursor, N);
  k_fill<<<(E + 255) / 256, 256, 0, stream>>>(src, dst, eattr, cursor, csrc, cattr, E);
  k_gstart<<<(N + 255) / 256, 256, 0, stream>>>(batch, gstart, N, GG);

  for (int l = 0; l < 4; ++l) {
    k_edge_agg<<<(N + 1) / 2, 256, 0, stream>>>(h, (const unsigned*)hb, cattr, csrc,
        offs, edgeW + (size_t)l * 16 * 128, edgeB + (size_t)l * 128, hpa, cstats, N);
    k_gemm<<<625, 256, 0, stream>>>(hpa,
        nnW + (size_t)l * 128 * 128, nnB + (size_t)l * 128, cstats, N);
    k_bn<<<q32, 256, 0, stream>>>(hpa, cstats,
        bnG + (size_t)l * 128, bnB + (size_t)l * 128, h, (l == 3) ? nullptr : hb, N);
  }
  k_poolfinal<<<GG, 256, 0, stream>>>(h, gstart, linW, linB, out);
}

// Round 6
// 1330.135 us; speedup vs baseline: 1.8920x; 1.1623x over previous
//
#include <hip/hip_runtime.h>
#include <hip/hip_fp16.h>
#include <math.h>

// Problem constants (from reference): N=100000, E=1600000, F_IN=8, H=128,
// L=4, E_FEAT=16, G=256, OUT=256. N/E derived from in_sizes at launch.
#define GG 256

__device__ __forceinline__ unsigned short f2bf(float x) {
  union { float f; unsigned u; } v; v.f = x;
  unsigned r = v.u + 0x7fff + ((v.u >> 16) & 1);   // round-to-nearest-even
  return (unsigned short)(r >> 16);
}

__device__ __forceinline__ unsigned pack_h2(float a, float b) {
  __half2 h = __floats2half2_rn(a, b);
  return *(unsigned*)&h;
}

// ---------- h = x @ emb_W + emb_b  ([N,8]@[8,128]); also writes bf16 shadow ----------
__global__ __launch_bounds__(256) void k_emb(const float* __restrict__ x,
    const float* __restrict__ W, const float* __restrict__ b,
    float* __restrict__ h, unsigned short* __restrict__ hb, int N) {
  int idx = blockIdx.x * 256 + threadIdx.x;      // one float4 of output per thread
  if (idx >= N * 32) return;
  int n = idx >> 5, q = idx & 31;
  const float* xr = x + (size_t)n * 8;
  float xs[8];
#pragma unroll
  for (int k = 0; k < 8; ++k) xs[k] = xr[k];
  float4 acc = ((const float4*)b)[q];
#pragma unroll
  for (int k = 0; k < 8; ++k) {
    float4 w = ((const float4*)(W + (size_t)k * 128))[q];
    acc.x += xs[k] * w.x; acc.y += xs[k] * w.y;
    acc.z += xs[k] * w.z; acc.w += xs[k] * w.w;
  }
  ((float4*)h)[idx] = acc;
  ushort4 hv4 = make_ushort4(f2bf(acc.x), f2bf(acc.y), f2bf(acc.z), f2bf(acc.w));
  *(ushort4*)(hb + (size_t)idx * 4) = hv4;
}

// ---------- convert edge weights to packed fp16: eW16[l][k][c] = (w[2c],w[2c+1]) ----------
__global__ __launch_bounds__(256) void k_wconv(const float* __restrict__ eW,
    unsigned* __restrict__ eW16) {           // 4*16*64 = 4096 pairs
  int i = blockIdx.x * 256 + threadIdx.x;
  if (i >= 4096) return;
  float2 wp = *(const float2*)(eW + (size_t)i * 2);
  eW16[i] = pack_h2(wp.x, wp.y);
}

// ---------- CSR build ----------
__global__ void k_hist(const int* __restrict__ dst, int* __restrict__ deg, int E) {
  int e = blockIdx.x * blockDim.x + threadIdx.x;
  if (e < E) atomicAdd(&deg[dst[e]], 1);
}

__global__ __launch_bounds__(256) void k_scan_reduce(const int* __restrict__ deg,
    int* __restrict__ bsum, int N) {
  __shared__ int sd[256];
  int i = blockIdx.x * 256 + threadIdx.x;
  sd[threadIdx.x] = (i < N) ? deg[i] : 0;
  __syncthreads();
  for (int s = 128; s > 0; s >>= 1) {
    if (threadIdx.x < s) sd[threadIdx.x] += sd[threadIdx.x + s];
    __syncthreads();
  }
  if (threadIdx.x == 0) bsum[blockIdx.x] = sd[0];
}

// single-block exclusive scan over nb (<=512) block sums
__global__ __launch_bounds__(512) void k_scan_mid(int* bsum, int nb) {
  __shared__ int sd[512];
  int t = threadIdx.x;
  int v = (t < nb) ? bsum[t] : 0;
  sd[t] = v; __syncthreads();
  for (int d = 1; d < 512; d <<= 1) {
    int xv = (t >= d) ? sd[t - d] : 0;
    __syncthreads();
    sd[t] += xv;
    __syncthreads();
  }
  if (t < nb) bsum[t] = sd[t] - v;   // exclusive
}

__global__ __launch_bounds__(256) void k_scan_final(const int* __restrict__ deg,
    const int* __restrict__ bsum, int* __restrict__ offs,
    int* __restrict__ cursor, int N) {
  __shared__ int sd[256];
  int t = threadIdx.x;
  int i = blockIdx.x * 256 + t;
  int v = (i < N) ? deg[i] : 0;
  sd[t] = v; __syncthreads();
  for (int d = 1; d < 256; d <<= 1) {           // Hillis-Steele inclusive scan
    int xv = (t >= d) ? sd[t - d] : 0;
    __syncthreads();
    sd[t] += xv;
    __syncthreads();
  }
  int off = bsum[blockIdx.x] + sd[t] - v;       // exclusive
  if (i < N) {
    offs[i] = off; cursor[i] = off;
    if (i == N - 1) offs[N] = off + v;
  }
}

// fill CSR: permute src + attr (converted to fp16, 32 B/edge) into dst order
__global__ void k_fill(const int* __restrict__ src, const int* __restrict__ dst,
    const float* __restrict__ attr, int* __restrict__ cursor,
    int* __restrict__ csrc, uint4* __restrict__ cattr16, int E) {
  int e = blockIdx.x * blockDim.x + threadIdx.x;
  if (e >= E) return;
  int d = dst[e];
  int pos = atomicAdd(&cursor[d], 1);
  csrc[pos] = src[e];
  const float4* a = (const float4*)(attr + (size_t)e * 16);
  float4 a0 = a[0], a1 = a[1], a2 = a[2], a3 = a[3];
  uint4 o0, o1;
  o0.x = pack_h2(a0.x, a0.y); o0.y = pack_h2(a0.z, a0.w);
  o0.z = pack_h2(a1.x, a1.y); o0.w = pack_h2(a1.z, a1.w);
  o1.x = pack_h2(a2.x, a2.y); o1.y = pack_h2(a2.z, a2.w);
  o1.z = pack_h2(a3.x, a3.y); o1.w = pack_h2(a3.z, a3.w);
  cattr16[(size_t)pos * 2] = o0;
  cattr16[(size_t)pos * 2 + 1] = o1;
}

// ---------- graph boundaries (batch is sorted) ----------
__global__ void k_gstart(const int* __restrict__ batch, int* __restrict__ gstart,
                         int N, int Gn) {
  int i = blockIdx.x * blockDim.x + threadIdx.x;
  if (i >= N) return;
  int b = batch[i];
  if (i == 0) { for (int g = 0; g <= b; ++g) gstart[g] = 0; }
  else { int bp = batch[i - 1]; for (int g = bp + 1; g <= b; ++g) gstart[g] = i; }
  if (i == N - 1) { for (int g = b + 1; g <= Gn; ++g) gstart[g] = N; }
}

// ---------- fused edge embed + gather + relu + aggregate ----------
// hpa[n] = h[n] + sum_{j in CSR(n)} relu( attr[j]@edge_W + edge_b + h[src[j]] )
// ONE WAVE per node, 2 columns per lane. Edge MLP in packed fp16
// (v_pk_fma_f16, weights pre-packed [16][64]); attrs scalar-loaded as fp16
// (32 B/edge, no duplication); gather = 1 bf16 dword per lane (full row/wave).
// Bias + accumulate in fp32. Block 0 zeroes BN stats buffer for k_gemm.
__global__ __launch_bounds__(256) void k_edge_agg(const float* __restrict__ h,
    const unsigned* __restrict__ hb32,       // bf16 shadow viewed as uint
    const uint4* __restrict__ cattr16, const int* __restrict__ csrc,
    const int* __restrict__ offs, const unsigned* __restrict__ eW16,
    const float* __restrict__ eb, float* __restrict__ hpa,
    float* __restrict__ cstats, int N) {
  int t = threadIdx.x;
  if (blockIdx.x == 0) cstats[t] = 0.f;    // 256 floats: colsum|colsumsq
  int n = blockIdx.x * 4 + (t >> 6);
  if (n >= N) return;
  int l = t & 63;                           // lane -> columns 2l, 2l+1
  __half2 w2[16];
#pragma unroll
  for (int k = 0; k < 16; ++k) {
    unsigned u = eW16[k * 64 + l];
    w2[k] = *(__half2*)&u;
  }
  float2 bias = *(const float2*)(eb + 2 * l);
  const unsigned* hb_l = hb32 + l;          // + s*64 per edge (row = 64 uints)
  int jb = offs[n], je = offs[n + 1];
  jb = __builtin_amdgcn_readfirstlane(jb);
  je = __builtin_amdgcn_readfirstlane(je);

#define EDGE(JJ, ACC)                                                       \
  {                                                                         \
    int s = csrc[(JJ)];                                                     \
    uint4 p0 = cattr16[(size_t)(JJ) * 2];                                   \
    uint4 p1 = cattr16[(size_t)(JJ) * 2 + 1];                               \
    unsigned u = hb_l[(size_t)s * 64];                                      \
    __half2 ev = __floats2half2_rn(0.f, 0.f);                               \
    const unsigned pw[8] = {p0.x, p0.y, p0.z, p0.w, p1.x, p1.y, p1.z, p1.w};\
    _Pragma("unroll")                                                       \
    for (int k = 0; k < 8; ++k) {                                           \
      __half2 ap = *(__half2*)&pw[k];                                       \
      ev = __hfma2(__half2half2(__low2half(ap)), w2[2 * k], ev);            \
      ev = __hfma2(__half2half2(__high2half(ap)), w2[2 * k + 1], ev);       \
    }                                                                       \
    float e0 = __low2float(ev), e1 = __high2float(ev);                      \
    union { unsigned uu; float ff; } c0, c1;                                \
    c0.uu = u << 16; c1.uu = u & 0xffff0000u;                               \
    ACC.x += fmaxf(e0 + bias.x + c0.ff, 0.f);                               \
    ACC.y += fmaxf(e1 + bias.y + c1.ff, 0.f);                               \
  }

  float2 acc0 = make_float2(0.f, 0.f), acc1 = acc0, acc2 = acc0, acc3 = acc0;
  int j = jb;
  for (; j + 4 <= je; j += 4) {
    EDGE(j, acc0)
    EDGE(j + 1, acc1)
    EDGE(j + 2, acc2)
    EDGE(j + 3, acc3)
  }
  for (; j < je; ++j) EDGE(j, acc0)
#undef EDGE
  size_t o = (size_t)n * 128 + 2 * l;
  float2 hvv = *(const float2*)(h + o);
  float2 res;
  res.x = hvv.x + ((acc0.x + acc1.x) + (acc2.x + acc3.x));
  res.y = hvv.y + ((acc0.y + acc1.y) + (acc2.y + acc3.y));
  *(float2*)(hpa + o) = res;
}

// ---------- in-place node GEMM: hpa <- hpa @ nn_W + nn_b, + fused BN stats ----------
// Grid-stride over 32-row chunks; 4 rows x 4 cols per thread; rows transposed
// in LDS so the k-step is 2 ds_read_b128 + 16 FMA. BN stats accumulate in
// registers across chunks; ONE block-level reduce + 256 atomics per block.
__global__ __launch_bounds__(256) void k_gemm(float* __restrict__ hpa,
    const float* __restrict__ W, const float* __restrict__ b,
    float* __restrict__ cstats, int N) {
  __shared__ float rowsT[128][36];   // [k][row], padded: stride 144B (16B-aligned)
  __shared__ float wbuf[16][128];
  int t = threadIdx.x;
  int rg = t >> 5;                   // row group 0..7 (4 rows each)
  int cq = (t & 31) * 4;             // column quad
  float4 bv = *(const float4*)(b + cq);
  float sA0 = 0.f, sA1 = 0.f, sA2 = 0.f, sA3 = 0.f;
  float sQ0 = 0.f, sQ1 = 0.f, sQ2 = 0.f, sQ3 = 0.f;
  int nchunks = (N + 31) / 32;
  int lr = t >> 3;                   // load row 0..31
  int lk = (t & 7) * 16;             // load k offset
  for (int chunk = blockIdx.x; chunk < nchunks; chunk += gridDim.x) {
    int row0 = chunk * 32;
    __syncthreads();                 // prev chunk's rowsT reads done
    {
      int row = row0 + lr;
      float4 v0, v1, v2, v3;
      if (row < N) {
        const float4* gp = (const float4*)(hpa + (size_t)row * 128 + lk);
        v0 = gp[0]; v1 = gp[1]; v2 = gp[2]; v3 = gp[3];
      } else {
        v0 = v1 = v2 = v3 = make_float4(0.f, 0.f, 0.f, 0.f);
      }
      rowsT[lk + 0][lr] = v0.x;  rowsT[lk + 1][lr] = v0.y;
      rowsT[lk + 2][lr] = v0.z;  rowsT[lk + 3][lr] = v0.w;
      rowsT[lk + 4][lr] = v1.x;  rowsT[lk + 5][lr] = v1.y;
      rowsT[lk + 6][lr] = v1.z;  rowsT[lk + 7][lr] = v1.w;
      rowsT[lk + 8][lr] = v2.x;  rowsT[lk + 9][lr] = v2.y;
      rowsT[lk + 10][lr] = v2.z; rowsT[lk + 11][lr] = v2.w;
      rowsT[lk + 12][lr] = v3.x; rowsT[lk + 13][lr] = v3.y;
      rowsT[lk + 14][lr] = v3.z; rowsT[lk + 15][lr] = v3.w;
    }
    float4 acc0 = make_float4(0.f, 0.f, 0.f, 0.f);
    float4 acc1 = acc0, acc2 = acc0, acc3 = acc0;
    for (int kc = 0; kc < 8; ++kc) {
      __syncthreads();
      float4* wb4 = (float4*)&wbuf[0][0];
      const float4* gw = (const float4*)(W + (size_t)kc * 16 * 128);
      wb4[t] = gw[t];
      wb4[t + 256] = gw[t + 256];
      __syncthreads();
#pragma unroll
      for (int k = 0; k < 16; ++k) {
        float4 rv = *(const float4*)&rowsT[kc * 16 + k][rg * 4];
        float4 wv = *(const float4*)&wbuf[k][cq];
        acc0.x += rv.x * wv.x; acc0.y += rv.x * wv.y;
        acc0.z += rv.x * wv.z; acc0.w += rv.x * wv.w;
        acc1.x += rv.y * wv.x; acc1.y += rv.y * wv.y;
        acc1.z += rv.y * wv.z; acc1.w += rv.y * wv.w;
        acc2.x += rv.z * wv.x; acc2.y += rv.z * wv.y;
        acc2.z += rv.z * wv.z; acc2.w += rv.z * wv.w;
        acc3.x += rv.w * wv.x; acc3.y += rv.w * wv.y;
        acc3.z += rv.w * wv.z; acc3.w += rv.w * wv.w;
      }
    }
    int rowb = row0 + rg * 4;
#define EMIT(ACC, I)                                                        \
    {                                                                       \
      ACC.x += bv.x; ACC.y += bv.y; ACC.z += bv.z; ACC.w += bv.w;           \
      if (rowb + (I) < N) {                                                 \
        *(float4*)(hpa + (size_t)(rowb + (I)) * 128 + cq) = ACC;            \
        sA0 += ACC.x; sA1 += ACC.y; sA2 += ACC.z; sA3 += ACC.w;             \
        sQ0 += ACC.x * ACC.x; sQ1 += ACC.y * ACC.y;                         \
        sQ2 += ACC.z * ACC.z; sQ3 += ACC.w * ACC.w;                         \
      }                                                                     \
    }
    EMIT(acc0, 0) EMIT(acc1, 1) EMIT(acc2, 2) EMIT(acc3, 3)
#undef EMIT
  }
  // block-level stats reduction (reuse rowsT as scratch: needs 2048 floats)
  __syncthreads();
  float* sd = &rowsT[0][0];
  *(float4*)&sd[rg * 128 + cq] = make_float4(sA0, sA1, sA2, sA3);
  *(float4*)&sd[1024 + rg * 128 + cq] = make_float4(sQ0, sQ1, sQ2, sQ3);
  __syncthreads();
  if (t < 128) {
    float s = 0.f, s2 = 0.f;
#pragma unroll
    for (int r = 0; r < 8; ++r) {
      s += sd[r * 128 + t];
      s2 += sd[1024 + r * 128 + t];
    }
    atomicAdd(&cstats[t], s);
    atomicAdd(&cstats[128 + t], s2);
  }
}

// ---------- BN apply + exact GELU + residual: h += gelu(bn(hc)); bf16 shadow ----------
__global__ __launch_bounds__(256) void k_bn(const float* __restrict__ hc,
    const float* __restrict__ cstats,
    const float* __restrict__ g, const float* __restrict__ bb,
    float* __restrict__ h, unsigned short* __restrict__ hb, int N) {
  int idx = blockIdx.x * 256 + threadIdx.x;
  if (idx >= N * 32) return;
  int q = idx & 31;
  float invN = 1.f / (float)N;
  float4 cs = ((const float4*)cstats)[q];
  float4 cq = ((const float4*)cstats)[q + 32];
  float4 gv = ((const float4*)g)[q];
  float4 bv = ((const float4*)bb)[q];
  float4 v = ((const float4*)hc)[idx];
  float4 hv = ((const float4*)h)[idx];
#define BN1(X)                                                      \
  { float mu = cs.X * invN;                                         \
    float var = cq.X * invN - mu * mu;                              \
    float xn = (v.X - mu) * rsqrtf(var + 1e-5f) * gv.X + bv.X;      \
    hv.X += 0.5f * xn * (1.f + erff(xn * 0.70710678118654752f)); }
  BN1(x) BN1(y) BN1(z) BN1(w)
#undef BN1
  ((float4*)h)[idx] = hv;
  if (hb) {
    ushort4 hv4 = make_ushort4(f2bf(hv.x), f2bf(hv.y), f2bf(hv.z), f2bf(hv.w));
    *(ushort4*)(hb + (size_t)idx * 4) = hv4;
  }
}

// ---------- rep[g] = (sum over nodes of graph g of h[n]) @ lin_W + cnt*lin_b ----------
__global__ __launch_bounds__(256) void k_poolfinal(const float* __restrict__ h,
    const int* __restrict__ gstart, const float* __restrict__ W,
    const float* __restrict__ b, float* __restrict__ out) {
  int g = blockIdx.x;
  int t = threadIdx.x, c = t & 127, half = t >> 7;
  int n0 = gstart[g], n1 = gstart[g + 1];
  float s = 0.f;
  for (int n = n0 + half; n < n1; n += 2) s += h[(size_t)n * 128 + c];
  __shared__ float ls[256];
  __shared__ float pr[128];
  ls[t] = s; __syncthreads();
  if (t < 128) pr[t] = ls[t] + ls[t + 128];
  __syncthreads();
  float cnt = (float)(n1 - n0);
  float acc = cnt * b[t];
#pragma unroll 8
  for (int k = 0; k < 128; ++k) acc += pr[k] * W[(size_t)k * 256 + t];
  out[(size_t)g * 256 + t] = acc;
}

extern "C" void kernel_launch(void* const* d_in, const int* in_sizes, int n_in,
                              void* d_out, int out_size, void* d_ws, size_t ws_size,
                              hipStream_t stream) {
  const float* x     = (const float*)d_in[0];
  const int*   eidx  = (const int*)d_in[1];
  const float* eattr = (const float*)d_in[2];
  const int*   batch = (const int*)d_in[3];
  const float* embW  = (const float*)d_in[4];
  const float* embB  = (const float*)d_in[5];
  const float* edgeW = (const float*)d_in[6];
  const float* edgeB = (const float*)d_in[7];
  const float* nnW   = (const float*)d_in[8];
  const float* nnB   = (const float*)d_in[9];
  const float* bnG   = (const float*)d_in[10];
  const float* bnB   = (const float*)d_in[11];
  const float* linW  = (const float*)d_in[12];
  const float* linB  = (const float*)d_in[13];
  float* out = (float*)d_out;

  int N = in_sizes[0] / 8;
  int E = in_sizes[1] / 2;
  const int* src = eidx;
  const int* dst = eidx + E;

  // workspace carve-up (~190 MB)
  char* wptr = (char*)d_ws;
  auto alloc = [&](size_t bytes) {
    char* p = wptr; wptr += (bytes + 255) & ~(size_t)255; return p;
  };
  float* h      = (float*)alloc((size_t)N * 128 * 4);
  float* hpa    = (float*)alloc((size_t)N * 128 * 4);   // also hc (in-place GEMM)
  unsigned short* hb = (unsigned short*)alloc((size_t)N * 128 * 2);  // bf16 shadow
  uint4* cattr16 = (uint4*)alloc((size_t)E * 32);       // fp16 attrs, 32 B/edge
  int*   csrc   = (int*)alloc((size_t)E * 4);
  int*   offs   = (int*)alloc((size_t)(N + 1) * 4);
  int*   cursor = (int*)alloc((size_t)N * 4);
  int*   deg    = (int*)alloc((size_t)N * 4);
  int nb = (N + 255) / 256;
  int*   bsum   = (int*)alloc((size_t)nb * 4);
  float* cstats = (float*)alloc(256 * 4);               // colsum | colsumsq
  unsigned* eW16 = (unsigned*)alloc(4096 * 4);          // [4][16][64] packed half2
  int*   gstart = (int*)alloc((size_t)(GG + 1) * 4);

  int q32 = (N * 32 + 255) / 256;

  hipMemsetAsync(deg, 0, (size_t)N * 4, stream);
  k_emb<<<q32, 256, 0, stream>>>(x, embW, embB, h, hb, N);
  k_wconv<<<16, 256, 0, stream>>>(edgeW, eW16);
  k_hist<<<(E + 255) / 256, 256, 0, stream>>>(dst, deg, E);
  k_scan_reduce<<<nb, 256, 0, stream>>>(deg, bsum, N);
  k_scan_mid<<<1, 512, 0, stream>>>(bsum, nb);
  k_scan_final<<<nb, 256, 0, stream>>>(deg, bsum, offs, cursor, N);
  k_fill<<<(E + 255) / 256, 256, 0, stream>>>(src, dst, eattr, cursor, csrc, cattr16, E);
  k_gstart<<<(N + 255) / 256, 256, 0, stream>>>(batch, gstart, N, GG);

  for (int l = 0; l < 4; ++l) {
    k_edge_agg<<<(N + 3) / 4, 256, 0, stream>>>(h, (const unsigned*)hb, cattr16, csrc,
        offs, eW16 + (size_t)l * 1024, edgeB + (size_t)l * 128, hpa, cstats, N);
    k_gemm<<<625, 256, 0, stream>>>(hpa,
        nnW + (size_t)l * 128 * 128, nnB + (size_t)l * 128, cstats, N);
    k_bn<<<q32, 256, 0, stream>>>(hpa, cstats,
        bnG + (size_t)l * 128, bnB + (size_t)l * 128, h, (l == 3) ? nullptr : hb, N);
  }
  k_poolfinal<<<GG, 256, 0, stream>>>(h, gstart, linW, linB, out);
}

// Round 7
// 1206.575 us; speedup vs baseline: 2.0857x; 1.1024x over previous
//
#include <hip/hip_runtime.h>
#include <hip/hip_fp16.h>
#include <math.h>

// Problem constants (from reference): N=100000, E=1600000, F_IN=8, H=128,
// L=4, E_FEAT=16, G=256, OUT=256. N/E derived from in_sizes at launch.
#define GG 256

typedef __attribute__((ext_vector_type(8))) short short8;
typedef __attribute__((ext_vector_type(4))) float f32x4;

__device__ __forceinline__ unsigned short f2bf(float x) {
  union { float f; unsigned u; } v; v.f = x;
  unsigned r = v.u + 0x7fff + ((v.u >> 16) & 1);   // round-to-nearest-even
  return (unsigned short)(r >> 16);
}

__device__ __forceinline__ unsigned pack_h2(float a, float b) {
  __half2 h = __floats2half2_rn(a, b);
  return *(unsigned*)&h;
}

// ---------- h = x @ emb_W + emb_b  ([N,8]@[8,128]); also writes bf16 shadow ----------
__global__ __launch_bounds__(256) void k_emb(const float* __restrict__ x,
    const float* __restrict__ W, const float* __restrict__ b,
    float* __restrict__ h, unsigned short* __restrict__ hb, int N) {
  int idx = blockIdx.x * 256 + threadIdx.x;      // one float4 of output per thread
  if (idx >= N * 32) return;
  int n = idx >> 5, q = idx & 31;
  const float* xr = x + (size_t)n * 8;
  float xs[8];
#pragma unroll
  for (int k = 0; k < 8; ++k) xs[k] = xr[k];
  float4 acc = ((const float4*)b)[q];
#pragma unroll
  for (int k = 0; k < 8; ++k) {
    float4 w = ((const float4*)(W + (size_t)k * 128))[q];
    acc.x += xs[k] * w.x; acc.y += xs[k] * w.y;
    acc.z += xs[k] * w.z; acc.w += xs[k] * w.w;
  }
  ((float4*)h)[idx] = acc;
  ushort4 hv4 = make_ushort4(f2bf(acc.x), f2bf(acc.y), f2bf(acc.z), f2bf(acc.w));
  *(ushort4*)(hb + (size_t)idx * 4) = hv4;
}

// ---------- convert edge weights to packed fp16: eW16[l][k][c] = (w[2c],w[2c+1]) ----------
__global__ __launch_bounds__(256) void k_wconv(const float* __restrict__ eW,
    unsigned* __restrict__ eW16) {           // 4*16*64 = 4096 pairs
  int i = blockIdx.x * 256 + threadIdx.x;
  if (i >= 4096) return;
  float2 wp = *(const float2*)(eW + (size_t)i * 2);
  eW16[i] = pack_h2(wp.x, wp.y);
}

// ---------- transpose nn_W to bf16: WT[l][n][k] = bf16(nn_W[l][k][n]) ----------
__global__ __launch_bounds__(256) void k_nnconv(const float* __restrict__ W,
    unsigned short* __restrict__ WT) {
  int i = blockIdx.x * 256 + threadIdx.x;    // i = ((l*128)+k)*128 + n
  if (i >= 4 * 128 * 128) return;
  int n = i & 127, k = (i >> 7) & 127, l = i >> 14;
  WT[((size_t)(l * 128 + n)) * 128 + k] = f2bf(W[i]);
}

// ---------- CSR build ----------
__global__ void k_hist(const int* __restrict__ dst, int* __restrict__ deg, int E) {
  int e = blockIdx.x * blockDim.x + threadIdx.x;
  if (e < E) atomicAdd(&deg[dst[e]], 1);
}

__global__ __launch_bounds__(256) void k_scan_reduce(const int* __restrict__ deg,
    int* __restrict__ bsum, int N) {
  __shared__ int sd[256];
  int i = blockIdx.x * 256 + threadIdx.x;
  sd[threadIdx.x] = (i < N) ? deg[i] : 0;
  __syncthreads();
  for (int s = 128; s > 0; s >>= 1) {
    if (threadIdx.x < s) sd[threadIdx.x] += sd[threadIdx.x + s];
    __syncthreads();
  }
  if (threadIdx.x == 0) bsum[blockIdx.x] = sd[0];
}

// single-block exclusive scan over nb (<=512) block sums
__global__ __launch_bounds__(512) void k_scan_mid(int* bsum, int nb) {
  __shared__ int sd[512];
  int t = threadIdx.x;
  int v = (t < nb) ? bsum[t] : 0;
  sd[t] = v; __syncthreads();
  for (int d = 1; d < 512; d <<= 1) {
    int xv = (t >= d) ? sd[t - d] : 0;
    __syncthreads();
    sd[t] += xv;
    __syncthreads();
  }
  if (t < nb) bsum[t] = sd[t] - v;   // exclusive
}

__global__ __launch_bounds__(256) void k_scan_final(const int* __restrict__ deg,
    const int* __restrict__ bsum, int* __restrict__ offs,
    int* __restrict__ cursor, int N) {
  __shared__ int sd[256];
  int t = threadIdx.x;
  int i = blockIdx.x * 256 + t;
  int v = (i < N) ? deg[i] : 0;
  sd[t] = v; __syncthreads();
  for (int d = 1; d < 256; d <<= 1) {           // Hillis-Steele inclusive scan
    int xv = (t >= d) ? sd[t - d] : 0;
    __syncthreads();
    sd[t] += xv;
    __syncthreads();
  }
  int off = bsum[blockIdx.x] + sd[t] - v;       // exclusive
  if (i < N) {
    offs[i] = off; cursor[i] = off;
    if (i == N - 1) offs[N] = off + v;
  }
}

// fill CSR: permute src + attr (converted to fp16, 32 B/edge) into dst order
__global__ void k_fill(const int* __restrict__ src, const int* __restrict__ dst,
    const float* __restrict__ attr, int* __restrict__ cursor,
    int* __restrict__ csrc, uint4* __restrict__ cattr16, int E) {
  int e = blockIdx.x * blockDim.x + threadIdx.x;
  if (e >= E) return;
  int d = dst[e];
  int pos = atomicAdd(&cursor[d], 1);
  csrc[pos] = src[e];
  const float4* a = (const float4*)(attr + (size_t)e * 16);
  float4 a0 = a[0], a1 = a[1], a2 = a[2], a3 = a[3];
  uint4 o0, o1;
  o0.x = pack_h2(a0.x, a0.y); o0.y = pack_h2(a0.z, a0.w);
  o0.z = pack_h2(a1.x, a1.y); o0.w = pack_h2(a1.z, a1.w);
  o1.x = pack_h2(a2.x, a2.y); o1.y = pack_h2(a2.z, a2.w);
  o1.z = pack_h2(a3.x, a3.y); o1.w = pack_h2(a3.z, a3.w);
  cattr16[(size_t)pos * 2] = o0;
  cattr16[(size_t)pos * 2 + 1] = o1;
}

// ---------- graph boundaries (batch is sorted) ----------
__global__ void k_gstart(const int* __restrict__ batch, int* __restrict__ gstart,
                         int N, int Gn) {
  int i = blockIdx.x * blockDim.x + threadIdx.x;
  if (i >= N) return;
  int b = batch[i];
  if (i == 0) { for (int g = 0; g <= b; ++g) gstart[g] = 0; }
  else { int bp = batch[i - 1]; for (int g = bp + 1; g <= b; ++g) gstart[g] = i; }
  if (i == N - 1) { for (int g = b + 1; g <= Gn; ++g) gstart[g] = N; }
}

// ---------- fused edge embed + gather + relu + aggregate ----------
// hpa16[n] = bf16( h[n] + sum_j relu( attr[j]@edge_W + edge_b + h[src[j]] ) )
// ONE WAVE per node, 2 columns per lane, packed-fp16 MLP, 8 gathers in flight.
__global__ __launch_bounds__(256) void k_edge_agg(const float* __restrict__ h,
    const unsigned* __restrict__ hb32,       // bf16 shadow viewed as uint
    const uint4* __restrict__ cattr16, const int* __restrict__ csrc,
    const int* __restrict__ offs, const unsigned* __restrict__ eW16,
    const float* __restrict__ eb, unsigned* __restrict__ hpa16,
    float* __restrict__ cstats, int N) {
  int t = threadIdx.x;
  if (blockIdx.x == 0) cstats[t] = 0.f;    // 256 floats: colsum|colsumsq
  int n = blockIdx.x * 4 + (t >> 6);
  if (n >= N) return;
  int l = t & 63;                           // lane -> columns 2l, 2l+1
  __half2 w2[16];
#pragma unroll
  for (int k = 0; k < 16; ++k) {
    unsigned u = eW16[k * 64 + l];
    w2[k] = *(__half2*)&u;
  }
  float2 bias = *(const float2*)(eb + 2 * l);
  const unsigned* hb_l = hb32 + l;          // + s*64 per edge (row = 64 uints)
  int jb = offs[n], je = offs[n + 1];
  jb = __builtin_amdgcn_readfirstlane(jb);
  je = __builtin_amdgcn_readfirstlane(je);

#define EDGE(JJ, ACC)                                                       \
  {                                                                         \
    int s = csrc[(JJ)];                                                     \
    uint4 p0 = cattr16[(size_t)(JJ) * 2];                                   \
    uint4 p1 = cattr16[(size_t)(JJ) * 2 + 1];                               \
    unsigned u = hb_l[(size_t)s * 64];                                      \
    __half2 ev = __floats2half2_rn(0.f, 0.f);                               \
    const unsigned pw[8] = {p0.x, p0.y, p0.z, p0.w, p1.x, p1.y, p1.z, p1.w};\
    _Pragma("unroll")                                                       \
    for (int k = 0; k < 8; ++k) {                                           \
      __half2 ap = *(__half2*)&pw[k];                                       \
      ev = __hfma2(__half2half2(__low2half(ap)), w2[2 * k], ev);            \
      ev = __hfma2(__half2half2(__high2half(ap)), w2[2 * k + 1], ev);       \
    }                                                                       \
    float e0 = __low2float(ev), e1 = __high2float(ev);                      \
    union { unsigned uu; float ff; } c0, c1;                                \
    c0.uu = u << 16; c1.uu = u & 0xffff0000u;                               \
    ACC.x += fmaxf(e0 + bias.x + c0.ff, 0.f);                               \
    ACC.y += fmaxf(e1 + bias.y + c1.ff, 0.f);                               \
  }

  float2 a0 = make_float2(0.f, 0.f), a1 = a0, a2 = a0, a3 = a0;
  float2 a4 = a0, a5 = a0, a6 = a0, a7 = a0;
  int j = jb;
  for (; j + 8 <= je; j += 8) {
    EDGE(j, a0) EDGE(j + 1, a1) EDGE(j + 2, a2) EDGE(j + 3, a3)
    EDGE(j + 4, a4) EDGE(j + 5, a5) EDGE(j + 6, a6) EDGE(j + 7, a7)
  }
  if (j + 4 <= je) {
    EDGE(j, a0) EDGE(j + 1, a1) EDGE(j + 2, a2) EDGE(j + 3, a3)
    j += 4;
  }
  for (; j < je; ++j) EDGE(j, a0)
#undef EDGE
  float2 hvv = *(const float2*)(h + (size_t)n * 128 + 2 * l);
  float rx = hvv.x + (((a0.x + a1.x) + (a2.x + a3.x)) + ((a4.x + a5.x) + (a6.x + a7.x)));
  float ry = hvv.y + (((a0.y + a1.y) + (a2.y + a3.y)) + ((a4.y + a5.y) + (a6.y + a7.y)));
  hpa16[(size_t)n * 64 + l] = ((unsigned)f2bf(ry) << 16) | (unsigned)f2bf(rx);
}

// ---------- MFMA node GEMM: hc = bf16(hpa) @ nn_W + nn_b, + fused BN stats ----------
// 128 rows/block, 4 waves x (2 row-tiles x 8 col-tiles) of 16x16x32 bf16 MFMA.
// A and WT (pre-transposed W, [n][k]) staged in LDS, rows padded +8 shorts
// (272 B stride -> 2-way bank aliasing, free). Stats: shfl-xor quad reduce ->
// LDS -> 256 atomics per block.
__global__ __launch_bounds__(256) void k_gemm_mfma(
    const unsigned short* __restrict__ A16, const unsigned short* __restrict__ WT16,
    const float* __restrict__ bias, float* __restrict__ hc,
    float* __restrict__ cstats, int N) {
  __shared__ short a_lds[128 * 136];
  __shared__ short w_lds[128 * 136];
  int t = threadIdx.x;
  int rowbase = blockIdx.x * 128;
  {
    int r = t >> 1;
    int off = (t & 1) * 64;              // shorts
    const short* ga = (const short*)A16 + (size_t)(rowbase + r) * 128 + off;
    short* la = &a_lds[r * 136 + off];
    const short* gw = (const short*)WT16 + (size_t)r * 128 + off;
    short* lw = &w_lds[r * 136 + off];
    if (rowbase + r < N) {
#pragma unroll
      for (int jj = 0; jj < 8; ++jj)
        *(uint4*)(la + jj * 8) = *(const uint4*)(ga + jj * 8);
    } else {
#pragma unroll
      for (int jj = 0; jj < 8; ++jj)
        *(uint4*)(la + jj * 8) = make_uint4(0, 0, 0, 0);
    }
#pragma unroll
    for (int jj = 0; jj < 8; ++jj)
      *(uint4*)(lw + jj * 8) = *(const uint4*)(gw + jj * 8);
  }
  __syncthreads();
  int w = t >> 6;
  int lane = t & 63;
  int l15 = lane & 15, quad = lane >> 4;
  f32x4 acc[2][8];
#pragma unroll
  for (int rt = 0; rt < 2; ++rt)
#pragma unroll
    for (int nt = 0; nt < 8; ++nt)
      acc[rt][nt] = (f32x4){0.f, 0.f, 0.f, 0.f};
#pragma unroll
  for (int kc = 0; kc < 4; ++kc) {
    int k0 = kc * 32 + quad * 8;
    short8 af0 = *(const short8*)&a_lds[(w * 32 + l15) * 136 + k0];
    short8 af1 = *(const short8*)&a_lds[(w * 32 + 16 + l15) * 136 + k0];
#pragma unroll
    for (int nt = 0; nt < 8; ++nt) {
      short8 bf = *(const short8*)&w_lds[(nt * 16 + l15) * 136 + k0];
      acc[0][nt] = __builtin_amdgcn_mfma_f32_16x16x32_bf16(af0, bf, acc[0][nt], 0, 0, 0);
      acc[1][nt] = __builtin_amdgcn_mfma_f32_16x16x32_bf16(af1, bf, acc[1][nt], 0, 0, 0);
    }
  }
  float sA[8], sQ[8];
#pragma unroll
  for (int nt = 0; nt < 8; ++nt) { sA[nt] = 0.f; sQ[nt] = 0.f; }
#pragma unroll
  for (int nt = 0; nt < 8; ++nt) {
    int col = nt * 16 + l15;
    float bv = bias[col];
#pragma unroll
    for (int rt = 0; rt < 2; ++rt) {
      int rbase = rowbase + w * 32 + rt * 16 + quad * 4;
#pragma unroll
      for (int reg = 0; reg < 4; ++reg) {
        int row = rbase + reg;
        float v = acc[rt][nt][reg] + bv;
        if (row < N) {
          hc[(size_t)row * 128 + col] = v;
          sA[nt] += v; sQ[nt] += v * v;
        }
      }
    }
  }
#pragma unroll
  for (int nt = 0; nt < 8; ++nt) {
    sA[nt] += __shfl_xor(sA[nt], 16);
    sA[nt] += __shfl_xor(sA[nt], 32);
    sQ[nt] += __shfl_xor(sQ[nt], 16);
    sQ[nt] += __shfl_xor(sQ[nt], 32);
  }
  __syncthreads();                    // done with a_lds/w_lds contents
  float* sdA = (float*)a_lds;         // [4][128]
  float* sdQ = (float*)w_lds;
  if (quad == 0) {
#pragma unroll
    for (int nt = 0; nt < 8; ++nt) {
      sdA[w * 128 + nt * 16 + l15] = sA[nt];
      sdQ[w * 128 + nt * 16 + l15] = sQ[nt];
    }
  }
  __syncthreads();
  if (t < 128) {
    float s = sdA[t] + sdA[128 + t] + sdA[256 + t] + sdA[384 + t];
    float s2 = sdQ[t] + sdQ[128 + t] + sdQ[256 + t] + sdQ[384 + t];
    atomicAdd(&cstats[t], s);
    atomicAdd(&cstats[128 + t], s2);
  }
}

// ---------- BN apply + exact GELU + residual: h += gelu(bn(hc)); bf16 shadow ----------
__global__ __launch_bounds__(256) void k_bn(const float* __restrict__ hc,
    const float* __restrict__ cstats,
    const float* __restrict__ g, const float* __restrict__ bb,
    float* __restrict__ h, unsigned short* __restrict__ hb, int N) {
  int idx = blockIdx.x * 256 + threadIdx.x;
  if (idx >= N * 32) return;
  int q = idx & 31;
  float invN = 1.f / (float)N;
  float4 cs = ((const float4*)cstats)[q];
  float4 cq = ((const float4*)cstats)[q + 32];
  float4 gv = ((const float4*)g)[q];
  float4 bv = ((const float4*)bb)[q];
  float4 v = ((const float4*)hc)[idx];
  float4 hv = ((const float4*)h)[idx];
#define BN1(X)                                                      \
  { float mu = cs.X * invN;                                         \
    float var = cq.X * invN - mu * mu;                              \
    float xn = (v.X - mu) * rsqrtf(var + 1e-5f) * gv.X + bv.X;      \
    hv.X += 0.5f * xn * (1.f + erff(xn * 0.70710678118654752f)); }
  BN1(x) BN1(y) BN1(z) BN1(w)
#undef BN1
  ((float4*)h)[idx] = hv;
  if (hb) {
    ushort4 hv4 = make_ushort4(f2bf(hv.x), f2bf(hv.y), f2bf(hv.z), f2bf(hv.w));
    *(ushort4*)(hb + (size_t)idx * 4) = hv4;
  }
}

// ---------- rep[g] = (sum over nodes of graph g of h[n]) @ lin_W + cnt*lin_b ----------
__global__ __launch_bounds__(256) void k_poolfinal(const float* __restrict__ h,
    const int* __restrict__ gstart, const float* __restrict__ W,
    const float* __restrict__ b, float* __restrict__ out) {
  int g = blockIdx.x;
  int t = threadIdx.x, c = t & 127, half = t >> 7;
  int n0 = gstart[g], n1 = gstart[g + 1];
  float s = 0.f;
  for (int n = n0 + half; n < n1; n += 2) s += h[(size_t)n * 128 + c];
  __shared__ float ls[256];
  __shared__ float pr[128];
  ls[t] = s; __syncthreads();
  if (t < 128) pr[t] = ls[t] + ls[t + 128];
  __syncthreads();
  float cnt = (float)(n1 - n0);
  float acc = cnt * b[t];
#pragma unroll 8
  for (int k = 0; k < 128; ++k) acc += pr[k] * W[(size_t)k * 256 + t];
  out[(size_t)g * 256 + t] = acc;
}

extern "C" void kernel_launch(void* const* d_in, const int* in_sizes, int n_in,
                              void* d_out, int out_size, void* d_ws, size_t ws_size,
                              hipStream_t stream) {
  const float* x     = (const float*)d_in[0];
  const int*   eidx  = (const int*)d_in[1];
  const float* eattr = (const float*)d_in[2];
  const int*   batch = (const int*)d_in[3];
  const float* embW  = (const float*)d_in[4];
  const float* embB  = (const float*)d_in[5];
  const float* edgeW = (const float*)d_in[6];
  const float* edgeB = (const float*)d_in[7];
  const float* nnW   = (const float*)d_in[8];
  const float* nnB   = (const float*)d_in[9];
  const float* bnG   = (const float*)d_in[10];
  const float* bnB   = (const float*)d_in[11];
  const float* linW  = (const float*)d_in[12];
  const float* linB  = (const float*)d_in[13];
  float* out = (float*)d_out;

  int N = in_sizes[0] / 8;
  int E = in_sizes[1] / 2;
  const int* src = eidx;
  const int* dst = eidx + E;

  // workspace carve-up (~220 MB)
  char* wptr = (char*)d_ws;
  auto alloc = [&](size_t bytes) {
    char* p = wptr; wptr += (bytes + 255) & ~(size_t)255; return p;
  };
  float* h      = (float*)alloc((size_t)N * 128 * 4);
  float* hc     = (float*)alloc((size_t)N * 128 * 4);   // fp32 GEMM output
  unsigned short* hb = (unsigned short*)alloc((size_t)N * 128 * 2);  // bf16 h shadow
  unsigned* hpa16 = (unsigned*)alloc((size_t)N * 64 * 4);  // bf16 h+agg (GEMM input)
  uint4* cattr16 = (uint4*)alloc((size_t)E * 32);       // fp16 attrs, 32 B/edge
  int*   csrc   = (int*)alloc((size_t)E * 4);
  int*   offs   = (int*)alloc((size_t)(N + 1) * 4);
  int*   cursor = (int*)alloc((size_t)N * 4);
  int*   deg    = (int*)alloc((size_t)N * 4);
  int nb = (N + 255) / 256;
  int*   bsum   = (int*)alloc((size_t)nb * 4);
  float* cstats = (float*)alloc(256 * 4);               // colsum | colsumsq
  unsigned* eW16 = (unsigned*)alloc(4096 * 4);          // [4][16][64] packed half2
  unsigned short* WT16 = (unsigned short*)alloc(4 * 128 * 128 * 2);  // bf16 W^T
  int*   gstart = (int*)alloc((size_t)(GG + 1) * 4);

  int q32 = (N * 32 + 255) / 256;

  hipMemsetAsync(deg, 0, (size_t)N * 4, stream);
  k_emb<<<q32, 256, 0, stream>>>(x, embW, embB, h, hb, N);
  k_wconv<<<16, 256, 0, stream>>>(edgeW, eW16);
  k_nnconv<<<256, 256, 0, stream>>>(nnW, WT16);
  k_hist<<<(E + 255) / 256, 256, 0, stream>>>(dst, deg, E);
  k_scan_reduce<<<nb, 256, 0, stream>>>(deg, bsum, N);
  k_scan_mid<<<1, 512, 0, stream>>>(bsum, nb);
  k_scan_final<<<nb, 256, 0, stream>>>(deg, bsum, offs, cursor, N);
  k_fill<<<(E + 255) / 256, 256, 0, stream>>>(src, dst, eattr, cursor, csrc, cattr16, E);
  k_gstart<<<(N + 255) / 256, 256, 0, stream>>>(batch, gstart, N, GG);

  int gblk = (N + 127) / 128;
  for (int l = 0; l < 4; ++l) {
    k_edge_agg<<<(N + 3) / 4, 256, 0, stream>>>(h, (const unsigned*)hb, cattr16, csrc,
        offs, eW16 + (size_t)l * 1024, edgeB + (size_t)l * 128, hpa16, cstats, N);
    k_gemm_mfma<<<gblk, 256, 0, stream>>>((const unsigned short*)hpa16,
        WT16 + (size_t)l * 128 * 128, nnB + (size_t)l * 128, hc, cstats, N);
    k_bn<<<q32, 256, 0, stream>>>(hc, cstats,
        bnG + (size_t)l * 128, bnB + (size_t)l * 128, h, (l == 3) ? nullptr : hb, N);
  }
  k_poolfinal<<<GG, 256, 0, stream>>>(h, gstart, linW, linB, out);
}